// Round 8
// baseline (350.449 us; speedup 1.0000x reference)
//
#include <hip/hip_runtime.h>

// LightweightConv1d: x (T,B,C) f32, weight (H,1,K) f32 (softmax over K), bias (C) f32
// out[t,b,c] = bias[c] + sum_k softmax(w[h])[k] * x[t-P+k, b, c],  h = c / (C/H)
//
// float4-streaming multi-accumulator: each thread owns 4 consecutive channels x
// TT=16 outputs and streams 46 float4 inputs, FMA-ing into 16 float4 accumulators.
// Why float4: R6 proved the compiler keeps ~1 load in flight per wave; with dword
// loads that is 256B & 62 VALU-cyc per 460-cyc latency window (54% duty = measured
// 50% VALUBusy). float4 gives 1024B & ~86 VALU-cyc per window -> ~88% duty and 4x
// bytes per outstanding load slot: latency-bound -> BW-bound.
// Wave = 32 channels of ONE head (weights in SGPR) x 8 batches, 8x128B coalesced.
#define T_DIM 2048
#define B_DIM 32
#define C_DIM 512
#define H_DIM 16
#define K_DIM 31
#define P_PAD 15
#define TT 16                      // t-outputs per thread (16 float4 accumulators)
#define JN (TT + K_DIM - 1)        // 46 streamed float4 inputs per thread
#define NC4 (B_DIM * C_DIM / 4)    // 4096 float4 between consecutive t

__global__ __launch_bounds__(256, 4)
void lwconv_kernel(const float4* __restrict__ x4, const float* __restrict__ weight,
                   const float* __restrict__ bias, float4* __restrict__ out4)
{
    const int wid  = __builtin_amdgcn_readfirstlane((int)(threadIdx.x >> 6));
    const int lane = threadIdx.x & 63;
    const int gw   = blockIdx.x * 4 + wid;        // global wave id (scalar)
    const int h    = gw & (H_DIM - 1);            // head (wave-uniform)
    const int bp   = (gw >> 4) & 3;               // batch octet (uniform)
    const int tblk = gw >> 6;                     // t-block 0..127 (uniform)
    const int c4l  = lane & 7;                    // float4-column within head
    const int bl   = lane >> 3;                   // batch within octet
    const int b    = (bp << 3) | bl;
    const int col4 = b * (C_DIM / 4) + (h << 3) + c4l;   // float4 index in a t-row

    // per-lane softmax of the head's 31 weights (uniform inputs), then -> SGPR
    float w[K_DIM];
    float m = -3.4e38f;
    #pragma unroll
    for (int k = 0; k < K_DIM; ++k) { w[k] = weight[h * K_DIM + k]; m = fmaxf(m, w[k]); }
    float s = 0.f;
    #pragma unroll
    for (int k = 0; k < K_DIM; ++k) { w[k] = __expf(w[k] - m); s += w[k]; }
    const float inv = 1.f / s;
    unsigned int ws[K_DIM];
    #pragma unroll
    for (int k = 0; k < K_DIM; ++k)
        ws[k] = __builtin_amdgcn_readfirstlane(__float_as_uint(w[k] * inv));

    const float4 bv = ((const float4*)bias)[(h << 3) + c4l];
    const int tb = tblk * TT;                     // first output t of this thread
    const float4* xp = x4 + col4;
    float4*       op = out4 + col4;

    float4 acc[TT];
    #pragma unroll
    for (int i = 0; i < TT; ++i) acc[i] = bv;

    // Stream 46 float4 inputs; input j feeds accs [j-30, j] clipped to [0,15].
    #pragma unroll
    for (int j = 0; j < JN; ++j) {
        const int t  = tb - P_PAD + j;            // block-uniform
        int tc = t < 0 ? 0 : (t >= T_DIM ? T_DIM - 1 : t);
        float4 v = xp[(size_t)tc * NC4];
        if (t < 0 || t >= T_DIM) { v.x = 0.f; v.y = 0.f; v.z = 0.f; v.w = 0.f; }
        const int ilo = (j - (K_DIM - 1)) > 0 ? (j - (K_DIM - 1)) : 0;
        const int ihi = j < (TT - 1) ? j : (TT - 1);
        #pragma unroll
        for (int i = ilo; i <= ihi; ++i) {
            const float wk = __uint_as_float(ws[j - i]);
            acc[i].x = fmaf(wk, v.x, acc[i].x);
            acc[i].y = fmaf(wk, v.y, acc[i].y);
            acc[i].z = fmaf(wk, v.z, acc[i].z);
            acc[i].w = fmaf(wk, v.w, acc[i].w);
        }
    }

    #pragma unroll
    for (int i = 0; i < TT; ++i)
        op[(size_t)(tb + i) * NC4] = acc[i];
}

extern "C" void kernel_launch(void* const* d_in, const int* in_sizes, int n_in,
                              void* d_out, int out_size, void* d_ws, size_t ws_size,
                              hipStream_t stream) {
    const float4* x4    = (const float4*)d_in[0];
    const float* weight = (const float*)d_in[1];
    const float* bias   = (const float*)d_in[2];
    float4* out4 = (float4*)d_out;
    // waves = H(16) * batch-octets(4) * t-blocks(128) = 8192 -> 2048 blocks of 4 waves
    dim3 grid(H_DIM * 4 * (T_DIM / TT) / 4);
    dim3 block(256);
    lwconv_kernel<<<grid, block, 0, stream>>>(x4, weight, bias, out4);
}

// Round 9
// 62.402 us; speedup vs baseline: 5.6160x; 5.6160x over previous
//
#include <hip/hip_runtime.h>

// LightweightConv1d: x (T,B,C) f32, weight (H,1,K) f32 (softmax over K), bias (C) f32
// out[t,b,c] = bias[c] + sum_k softmax(w[h])[k] * x[t-P+k, b, c],  h = c / (C/H)
//
// LDS-staged form. R1-R8 lesson: register-carried windows remat (R3/R4), big
// accumulator sets spill (R5/R8), and the compiler keeps ~1 global load in
// flight per wave -> 50% VALU duty at ~460cyc latency (R6). Fix: stage x tiles
// into LDS via global_load_lds (no VGPR cost, 6 async 16B/lane loads per wave
// issued back-to-back), then stream from LDS (~120cyc latency, immediate-offset
// ds_read_b32). 24KB/block -> 6 blocks/CU -> 6 waves/SIMD saturate VALU even
// with serialized read->FMA. Per-thread state: 16 scalar accs -> no pressure.
#define T_DIM 2048
#define B_DIM 32
#define C_DIM 512
#define H_DIM 16
#define K_DIM 31
#define P_PAD 15
#define TBLK 64                    // output t-steps per block
#define ROWS 96                    // TBLK + 30 halo, padded to 96 (stage granule 4 rows)
#define CT 64                      // columns (floats) per block = one 256B segment
#define NCOL (B_DIM * C_DIM)       // 16384 floats between consecutive t

__global__ __launch_bounds__(256, 6)
void lwconv_kernel(const float* __restrict__ x, const float* __restrict__ weight,
                   const float* __restrict__ bias, float* __restrict__ out)
{
    __shared__ float smem[ROWS * CT];   // 24 KB, row-major [96][64]

    const int tid  = threadIdx.x;
    const int w    = tid >> 6;          // wave 0..3
    const int lane = tid & 63;
    const int bid  = blockIdx.x;
    const int tt   = bid & 31;          // t-tile 0..31
    const int ct   = bid >> 5;          // column tile 0..255 (= b*8 + channel-octet)
    const int colbase = ct * CT;
    const int t0   = tt * TBLK;

    // ---- stage 96 rows x 256B into LDS: 6 global_load_lds per wave, 16B/lane.
    // Lane i of load l covers row rbase+l*4+(i>>4), bytes (i&15)*16 of that row;
    // LDS dest (wave-uniform base + lane*16) is exactly row-major [4][64] floats.
    {
        const int rbase = w * 24;       // this wave stages rows [rbase, rbase+24)
        const float* src0 = x + colbase + ((lane & 15) << 2);
        #pragma unroll
        for (int l = 0; l < 6; ++l) {
            const int r = rbase + (l << 2) + (lane >> 4);
            int tg = t0 - P_PAD + r;                       // clamp; zeroed at compute
            tg = tg < 0 ? 0 : (tg >= T_DIM ? T_DIM - 1 : tg);
            const float* src = src0 + (size_t)tg * NCOL;
            __builtin_amdgcn_global_load_lds(
                (const __attribute__((address_space(1))) void*)src,
                (__attribute__((address_space(3))) void*)&smem[(rbase + (l << 2)) * CT],
                16, 0, 0);
        }
    }

    // wave -> (head, t-quarter pair): each wave covers ONE head's 32 columns.
    const int hloc = w & 1;
    const int tq   = ((w >> 1) << 1) | (lane >> 5);    // t-quarter 0..3
    const int cl   = (hloc << 5) | (lane & 31);        // column 0..63
    const int hg   = ((ct & 7) << 1) | hloc;           // global head (wave-uniform)

    // softmax of this head's 31 weights -> SGPR, computed while loads fly
    float wt[K_DIM];
    float m = -3.4e38f;
    #pragma unroll
    for (int k = 0; k < K_DIM; ++k) { wt[k] = weight[hg * K_DIM + k]; m = fmaxf(m, wt[k]); }
    float s = 0.f;
    #pragma unroll
    for (int k = 0; k < K_DIM; ++k) { wt[k] = __expf(wt[k] - m); s += wt[k]; }
    const float inv = 1.f / s;
    unsigned int ws[K_DIM];
    #pragma unroll
    for (int k = 0; k < K_DIM; ++k)
        ws[k] = __builtin_amdgcn_readfirstlane(__float_as_uint(wt[k] * inv));

    asm volatile("s_waitcnt vmcnt(0)" ::: "memory");
    __syncthreads();

    const float bv = bias[((ct & 7) << 6) + cl];
    float acc[16];
    #pragma unroll
    for (int i = 0; i < 16; ++i) acc[i] = bv;

    // stream 46 LDS rows; input j feeds accs [j-30, j] clipped to [0,15].
    // ds_read_b32 with compile-time offsets, stride 256B: lanes cover each bank
    // exactly twice (2-way = free). Rows tq*16 .. tq*16+45 <= 93 < 96.
    const float* sp = &smem[(tq << 4) * CT + cl];
    const int tbase = t0 + (tq << 4) - P_PAD;          // global t of j=0

    if (tt == 0 || tt == 31) {
        #pragma unroll
        for (int j = 0; j < 46; ++j) {
            float v = sp[j * CT];
            const int t = tbase + j;
            if (t < 0 || t >= T_DIM) v = 0.f;          // boundary tiles only
            const int ilo = (j - 30) > 0 ? (j - 30) : 0;
            const int ihi = j < 15 ? j : 15;
            #pragma unroll
            for (int i = ilo; i <= ihi; ++i)
                acc[i] = fmaf(__uint_as_float(ws[j - i]), v, acc[i]);
        }
    } else {
        #pragma unroll
        for (int j = 0; j < 46; ++j) {
            float v = sp[j * CT];
            const int ilo = (j - 30) > 0 ? (j - 30) : 0;
            const int ihi = j < 15 ? j : 15;
            #pragma unroll
            for (int i = ilo; i <= ihi; ++i)
                acc[i] = fmaf(__uint_as_float(ws[j - i]), v, acc[i]);
        }
    }

    float* op = out + (size_t)(t0 + (tq << 4)) * NCOL + colbase + cl;
    #pragma unroll
    for (int i = 0; i < 16; ++i)
        op[(size_t)i * NCOL] = acc[i];
}

extern "C" void kernel_launch(void* const* d_in, const int* in_sizes, int n_in,
                              void* d_out, int out_size, void* d_ws, size_t ws_size,
                              hipStream_t stream) {
    const float* x      = (const float*)d_in[0];
    const float* weight = (const float*)d_in[1];
    const float* bias   = (const float*)d_in[2];
    float* out = (float*)d_out;
    // grid: 256 column-tiles x 32 t-tiles = 8192 blocks of 256 threads
    dim3 grid((NCOL / CT) * (T_DIM / TBLK));
    dim3 block(256);
    lwconv_kernel<<<grid, block, 0, stream>>>(x, weight, bias, out);
}